// Round 8
// baseline (62.482 us; speedup 1.0000x reference)
//
#include <hip/hip_runtime.h>
#include <math.h>

#define EPS 1e-6f

typedef float f32x4 __attribute__((ext_vector_type(4)));

// Input: feat_map [T=32][D=256][H=56][W=56] fp32. float4 view: per-t 200704; slice 784.
// 12544 = 16*784.
//
// A/B probe round: two reduce dispatches (serialized on stream), 784 blocks x 256 thr
// each, 16 t's each. Variant NT uses non-temporal loads (nt), variant NN normal.
// Per-thread: fixed (h,v); 16 asm global_load_dwordx4 fire-and-forget, counted
// vmcnt waits (8 then 0), sched_barrier after each (rule #18). Epilogue: LDS
// histogram (224 floats) -> global atomicAdd into gsums[t][arr][56].
//
// ws: gsums [32][4][56] floats (28672 B), memset per launch.
// out: [0]=tot, then log10(ga1)[32*56], ga2, ga3, ga4.

#define GEN_REDUCE(NAME, NTSTR)                                                      \
__global__ __launch_bounds__(256) void NAME(const float* __restrict__ f,             \
                                            float* __restrict__ gsums,               \
                                            int t_base) {                            \
    const int b   = blockIdx.x;            /* 0..783 */                              \
    const int t   = t_base + b / 49;                                                 \
    const int tid = threadIdx.x;                                                     \
    const int r   = (b % 49) * 256 + tid;  /* 0..12543 */                            \
    const int pos = r % 784;                                                         \
    const int h   = pos / 14;                                                        \
    const int v   = pos % 14;                                                        \
                                                                                     \
    const f32x4* p = reinterpret_cast<const f32x4*>(f) + (size_t)t * 200704 + r;     \
                                                                                     \
    f32x4 x0, x1, x2, x3, x4, x5, x6, x7;                                            \
    f32x4 y0, y1, y2, y3, y4, y5, y6, y7;                                            \
                                                                                     \
    asm volatile("global_load_dwordx4 %0, %1, off " NTSTR                            \
                 : "=v"(x0) : "v"(p + (size_t)0 * 12544) : "memory");                \
    asm volatile("global_load_dwordx4 %0, %1, off " NTSTR                            \
                 : "=v"(x1) : "v"(p + (size_t)1 * 12544) : "memory");                \
    asm volatile("global_load_dwordx4 %0, %1, off " NTSTR                            \
                 : "=v"(x2) : "v"(p + (size_t)2 * 12544) : "memory");                \
    asm volatile("global_load_dwordx4 %0, %1, off " NTSTR                            \
                 : "=v"(x3) : "v"(p + (size_t)3 * 12544) : "memory");                \
    asm volatile("global_load_dwordx4 %0, %1, off " NTSTR                            \
                 : "=v"(x4) : "v"(p + (size_t)4 * 12544) : "memory");                \
    asm volatile("global_load_dwordx4 %0, %1, off " NTSTR                            \
                 : "=v"(x5) : "v"(p + (size_t)5 * 12544) : "memory");                \
    asm volatile("global_load_dwordx4 %0, %1, off " NTSTR                            \
                 : "=v"(x6) : "v"(p + (size_t)6 * 12544) : "memory");                \
    asm volatile("global_load_dwordx4 %0, %1, off " NTSTR                            \
                 : "=v"(x7) : "v"(p + (size_t)7 * 12544) : "memory");                \
    asm volatile("global_load_dwordx4 %0, %1, off " NTSTR                            \
                 : "=v"(y0) : "v"(p + (size_t)8 * 12544) : "memory");                \
    asm volatile("global_load_dwordx4 %0, %1, off " NTSTR                            \
                 : "=v"(y1) : "v"(p + (size_t)9 * 12544) : "memory");                \
    asm volatile("global_load_dwordx4 %0, %1, off " NTSTR                            \
                 : "=v"(y2) : "v"(p + (size_t)10 * 12544) : "memory");               \
    asm volatile("global_load_dwordx4 %0, %1, off " NTSTR                            \
                 : "=v"(y3) : "v"(p + (size_t)11 * 12544) : "memory");               \
    asm volatile("global_load_dwordx4 %0, %1, off " NTSTR                            \
                 : "=v"(y4) : "v"(p + (size_t)12 * 12544) : "memory");               \
    asm volatile("global_load_dwordx4 %0, %1, off " NTSTR                            \
                 : "=v"(y5) : "v"(p + (size_t)13 * 12544) : "memory");               \
    asm volatile("global_load_dwordx4 %0, %1, off " NTSTR                            \
                 : "=v"(y6) : "v"(p + (size_t)14 * 12544) : "memory");               \
    asm volatile("global_load_dwordx4 %0, %1, off " NTSTR                            \
                 : "=v"(y7) : "v"(p + (size_t)15 * 12544) : "memory");               \
                                                                                     \
    float s10 = 0.f, s11 = 0.f, s12 = 0.f, s13 = 0.f;                                \
    float s20 = 0.f, s21 = 0.f, s22 = 0.f, s23 = 0.f;                                \
                                                                                     \
    asm volatile("s_waitcnt vmcnt(8)" ::: "memory");                                 \
    __builtin_amdgcn_sched_barrier(0);                                               \
    ACC(x0); ACC(x1); ACC(x2); ACC(x3);                                              \
    ACC(x4); ACC(x5); ACC(x6); ACC(x7);                                              \
                                                                                     \
    asm volatile("s_waitcnt vmcnt(0)" ::: "memory");                                 \
    __builtin_amdgcn_sched_barrier(0);                                               \
    ACC(y0); ACC(y1); ACC(y2); ACC(y3);                                              \
    ACC(y4); ACC(y5); ACC(y6); ACC(y7);                                              \
                                                                                     \
    __shared__ float ls[224];                                                        \
    if (tid < 224) ls[tid] = 0.f;                                                    \
    __syncthreads();                                                                 \
                                                                                     \
    atomicAdd(&ls[h],      s10 + s11 + s12 + s13);                                   \
    atomicAdd(&ls[56 + h], s20 + s21 + s22 + s23);                                   \
    atomicAdd(&ls[112 + 4 * v + 0], s10);                                            \
    atomicAdd(&ls[112 + 4 * v + 1], s11);                                            \
    atomicAdd(&ls[112 + 4 * v + 2], s12);                                            \
    atomicAdd(&ls[112 + 4 * v + 3], s13);                                            \
    atomicAdd(&ls[168 + 4 * v + 0], s20);                                            \
    atomicAdd(&ls[168 + 4 * v + 1], s21);                                            \
    atomicAdd(&ls[168 + 4 * v + 2], s22);                                            \
    atomicAdd(&ls[168 + 4 * v + 3], s23);                                            \
    __syncthreads();                                                                 \
                                                                                     \
    if (tid < 224) atomicAdd(&gsums[t * 224 + tid], ls[tid]);                        \
}

#define ACC(B)                                        \
    do {                                              \
        s10 += (B).x; s11 += (B).y;                   \
        s12 += (B).z; s13 += (B).w;                   \
        s20 += (B).x * (B).x; s21 += (B).y * (B).y;   \
        s22 += (B).z * (B).z; s23 += (B).w * (B).w;   \
    } while (0)

GEN_REDUCE(loc_reduce_nt, "nt")   // non-temporal variant, t 0..15
GEN_REDUCE(loc_reduce_nn, "")     // control, t 16..31

#undef ACC
#undef GEN_REDUCE

__global__ __launch_bounds__(64) void loc_finalize(const float* __restrict__ gsums,
                                                   float* __restrict__ out) {
    const int tid  = threadIdx.x;
    const int t    = tid & 31;
    const bool isW = tid >= 32;

    const float* s1 = &gsums[t * 224 + (isW ? 112 : 0)];
    const float* s2 = &gsums[t * 224 + (isW ? 168 : 56)];
    float* osuf = out + 1 + (isW ? 3584 : 0)    + t * 56;  // ga1 / ga3
    float* opre = out + 1 + (isW ? 5376 : 1792) + t * 56;  // ga2 / ga4

    const float n_per = 14336.f;  // D*W == D*H
    float part = 0.f;

    float a1 = 0.f, a2 = 0.f;
    for (int i = 55; i >= 0; --i) {            // suffix
        a1 += s1[i]; a2 += s2[i];
        const float n  = n_per * (float)(56 - i);
        const float ga = sqrtf(a2 + 2.0f * EPS * a1 + (EPS * EPS) * n);
        osuf[i] = log10f(ga);
        part += ga + EPS;
    }
    a1 = 0.f; a2 = 0.f;
    for (int i = 0; i < 56; ++i) {             // prefix
        a1 += s1[i]; a2 += s2[i];
        const float n  = n_per * (float)(i + 1);
        const float ga = sqrtf(a2 + 2.0f * EPS * a1 + (EPS * EPS) * n);
        opre[i] = log10f(ga);
        part += ga + EPS;
    }

    #pragma unroll
    for (int off = 32; off; off >>= 1) part += __shfl_down(part, off);
    if (tid == 0) out[0] = part * (1.0f / 128.0f);  // /T /4
}

extern "C" void kernel_launch(void* const* d_in, const int* in_sizes, int n_in,
                              void* d_out, int out_size, void* d_ws, size_t ws_size,
                              hipStream_t stream) {
    const float* f = (const float*)d_in[0];
    float* out = (float*)d_out;
    float* ws  = (float*)d_ws;

    hipMemsetAsync(d_ws, 0, 7168 * sizeof(float), stream);
    loc_reduce_nt<<<dim3(784), dim3(256), 0, stream>>>(f, ws, 0);
    loc_reduce_nn<<<dim3(784), dim3(256), 0, stream>>>(f, ws, 16);
    loc_finalize<<<dim3(1), dim3(64), 0, stream>>>(ws, out);
}

// Round 9
// 49.123 us; speedup vs baseline: 1.2720x; 1.2720x over previous
//
#include <hip/hip_runtime.h>
#include <math.h>

#define EPS 1e-6f

typedef float f32x4 __attribute__((ext_vector_type(4)));
typedef const __attribute__((address_space(1))) float GF;
typedef __attribute__((address_space(3))) float LF;

// Input: feat_map [T=32][D=256][H=56][W=56] fp32. Slice = 3136 floats = 784 float4.
//
// loc_reduce: 256 blocks (1/CU), bid = t*8+dg; block sweeps slices [dg*32, dg*32+32)
//   of t (392 KB contiguous) via global_load_lds (direct-to-LDS DMA, bypassing the
//   per-CU VGPR-return path that caps plain loads at ~2.5 TB/s). Double-buffered
//   4-slice rounds; each wave stages exactly what it consumes (lane-linear) so the
//   pipeline needs NO barriers — only per-wave counted s_waitcnt vmcnt(4).
//   Thread tid<784 keeps fixed pos=tid -> (h=tid/14, v=tid%14); registers accumulate
//   all 32 slices; epilogue: LDS histogram -> ws[bid*224+k] direct store (no memset).
//
// ws partials: [bid][arr(0:s1h,1:s2h,2:s1w,3:s2w)][56]  (256*224 floats)
// out: [0]=tot, then log10(ga1)[32*56], ga2, ga3, ga4.

__global__ __launch_bounds__(832) void loc_reduce(const float* __restrict__ f,
                                                  float* __restrict__ ws) {
    const int bid = blockIdx.x;          // 0..255
    const int t   = bid >> 3;
    const int dg  = bid & 7;
    const int tid = threadIdx.x;

    __shared__ float buf[2][12544];      // 2 x 4 slices x 3136 floats = 100,352 B
    __shared__ float ls[224];

    for (int k = tid; k < 224; k += 832) ls[k] = 0.f;

    float s10 = 0.f, s11 = 0.f, s12 = 0.f, s13 = 0.f;
    float s20 = 0.f, s21 = 0.f, s22 = 0.f, s23 = 0.f;
    int h = 0, v = 0;

    if (tid < 784) {
        h = tid / 14;
        v = tid % 14;
        const float* gbase = f + (size_t)t * 802816 + (size_t)dg * 32 * 3136
                               + (size_t)tid * 4;          // per-lane global src
        const int wbase = (tid >> 6) << 8;                 // wave-uniform LDS float offset

#define STAGE(r, hf)                                                           \
        do {                                                                   \
            const float* _s = gbase + (size_t)(r) * 4 * 3136;                  \
            _Pragma("unroll")                                                  \
            for (int s = 0; s < 4; ++s)                                        \
                __builtin_amdgcn_global_load_lds(                              \
                    (GF*)(_s + s * 3136),                                      \
                    (LF*)(&buf[hf][s * 3136 + wbase]), 16, 0, 0);              \
        } while (0)

#define CONSUME(hf)                                                            \
        do {                                                                   \
            _Pragma("unroll")                                                  \
            for (int s = 0; s < 4; ++s) {                                      \
                f32x4 x = *(const f32x4*)&buf[hf][s * 3136 + tid * 4];         \
                s10 += x.x; s11 += x.y; s12 += x.z; s13 += x.w;                \
                s20 += x.x * x.x; s21 += x.y * x.y;                            \
                s22 += x.z * x.z; s23 += x.w * x.w;                            \
            }                                                                  \
        } while (0)

        STAGE(0, 0);
        #pragma unroll
        for (int r = 0; r < 8; ++r) {
            if (r < 7) {
                STAGE(r + 1, (r + 1) & 1);
                asm volatile("s_waitcnt vmcnt(4)" ::: "memory");  // round r landed
            } else {
                asm volatile("s_waitcnt vmcnt(0)" ::: "memory");
            }
            __builtin_amdgcn_sched_barrier(0);
            CONSUME(r & 1);
        }
#undef STAGE
#undef CONSUME
    }

    __syncthreads();   // ls zero-init complete

    if (tid < 784) {
        atomicAdd(&ls[h],      s10 + s11 + s12 + s13);
        atomicAdd(&ls[56 + h], s20 + s21 + s22 + s23);
        atomicAdd(&ls[112 + 4 * v + 0], s10);
        atomicAdd(&ls[112 + 4 * v + 1], s11);
        atomicAdd(&ls[112 + 4 * v + 2], s12);
        atomicAdd(&ls[112 + 4 * v + 3], s13);
        atomicAdd(&ls[168 + 4 * v + 0], s20);
        atomicAdd(&ls[168 + 4 * v + 1], s21);
        atomicAdd(&ls[168 + 4 * v + 2], s22);
        atomicAdd(&ls[168 + 4 * v + 3], s23);
    }
    __syncthreads();

    if (tid < 224) ws[(size_t)bid * 224 + tid] = ls[tid];
}

__global__ __launch_bounds__(1024) void loc_finalize(const float* __restrict__ ws,
                                                     float* __restrict__ out) {
    __shared__ float sums[7168];  // [t][arr][56]
    const int tid = threadIdx.x;

    // Phase 1: fold the 8 dg partials per t (coalesced; 7 outputs/thread).
    #pragma unroll
    for (int k = 0; k < 7; ++k) {
        const int o  = tid + 1024 * k;   // o = t*224 + k2
        const int t  = o / 224;
        const int k2 = o % 224;
        float a = 0.f;
        #pragma unroll
        for (int dg = 0; dg < 8; ++dg)
            a += ws[(size_t)(t * 8 + dg) * 224 + k2];
        sums[o] = a;
    }
    __syncthreads();

    // Phase 2: 64 threads = (t 0..31) x (H-axis / W-axis); serial 56-elem scans.
    if (tid < 64) {
        const int t    = tid & 31;
        const bool isW = tid >= 32;

        const float* s1 = &sums[t * 224 + (isW ? 112 : 0)];
        const float* s2 = &sums[t * 224 + (isW ? 168 : 56)];
        float* osuf = out + 1 + (isW ? 3584 : 0)    + t * 56;  // ga1 / ga3
        float* opre = out + 1 + (isW ? 5376 : 1792) + t * 56;  // ga2 / ga4

        const float n_per = 14336.f;  // D*W == D*H
        float part = 0.f;

        float a1 = 0.f, a2 = 0.f;
        for (int i = 55; i >= 0; --i) {            // suffix
            a1 += s1[i]; a2 += s2[i];
            const float n  = n_per * (float)(56 - i);
            const float ga = sqrtf(a2 + 2.0f * EPS * a1 + (EPS * EPS) * n);
            osuf[i] = log10f(ga);
            part += ga + EPS;
        }
        a1 = 0.f; a2 = 0.f;
        for (int i = 0; i < 56; ++i) {             // prefix
            a1 += s1[i]; a2 += s2[i];
            const float n  = n_per * (float)(i + 1);
            const float ga = sqrtf(a2 + 2.0f * EPS * a1 + (EPS * EPS) * n);
            opre[i] = log10f(ga);
            part += ga + EPS;
        }

        #pragma unroll
        for (int off = 32; off; off >>= 1) part += __shfl_down(part, off);
        if (tid == 0) out[0] = part * (1.0f / 128.0f);  // /T /4
    }
}

extern "C" void kernel_launch(void* const* d_in, const int* in_sizes, int n_in,
                              void* d_out, int out_size, void* d_ws, size_t ws_size,
                              hipStream_t stream) {
    const float* f = (const float*)d_in[0];
    float* out = (float*)d_out;
    float* ws  = (float*)d_ws;

    loc_reduce<<<dim3(256), dim3(832), 0, stream>>>(f, ws);
    loc_finalize<<<dim3(1), dim3(1024), 0, stream>>>(ws, out);
}